// Round 2
// baseline (487.562 us; speedup 1.0000x reference)
//
#include <hip/hip_runtime.h>
#include <math.h>

#define DD 64
#define NN 512
#define LL 1024
#define EPSF 1e-5f

// ---------------------------------------------------------------------------
// Kernel A: block per l. Stage 256 rows (n-chunk) into LDS with coalesced
// 256B-contiguous bursts, then thread t = row n. LN, k/v projections
// (wave-uniform s_load weights), xbar accumulated in regs, reduced in LDS.
// ---------------------------------------------------------------------------
__global__ __launch_bounds__(256) void kA(
    const float* __restrict__ msa, const float* __restrict__ lnw, const float* __restrict__ lnb,
    const float* __restrict__ Wk, const float* __restrict__ Wv,
    float* __restrict__ kb, float* __restrict__ vb, float* __restrict__ xbar)
{
  __shared__ float4 X4[256][17];   // 69632 B; also reused as reduction scratch
  const int l = blockIdx.x;
  const int t = threadIdx.x;

  float xacc[DD];
#pragma unroll
  for (int d = 0; d < DD; ++d) xacc[d] = 0.f;

#pragma unroll 1
  for (int c = 0; c < 2; ++c) {
    const int n0 = c * 256;
    const int rr = t >> 4, ff = t & 15;
    // stage: per instruction a wave reads 4 rows x 256B contiguous each
#pragma unroll
    for (int j = 0; j < 16; ++j) {
      const int r = j * 16 + rr;
      X4[r][ff] = *(const float4*)(msa + ((size_t)(n0 + r) * LL + l) * DD + ff * 4);
    }
    __syncthreads();

    // thread t owns staged row t (global n = n0 + t)
    float s = 0.f, s2 = 0.f;
#pragma unroll
    for (int i = 0; i < 16; ++i) {
      const float4 f = X4[t][i];
      s += (f.x + f.y) + (f.z + f.w);
      s2 = fmaf(f.x, f.x, s2); s2 = fmaf(f.y, f.y, s2);
      s2 = fmaf(f.z, f.z, s2); s2 = fmaf(f.w, f.w, s2);
    }
    const float mu = s * (1.f / DD);
    const float rs = rsqrtf(fmaf(-mu, mu, s2 * (1.f / DD)) + EPSF);

    float ka[8], va[8];
#pragma unroll
    for (int j = 0; j < 8; ++j) { ka[j] = 0.f; va[j] = 0.f; }

#pragma unroll
    for (int i = 0; i < 16; ++i) {
      const float4 f = X4[t][i];
#define KA_STEP(comp, c4)                                            \
      {                                                              \
        const int d = 4 * i + (c4);                                  \
        const float xn = fmaf((f.comp - mu) * rs, lnw[d], lnb[d]);   \
        xacc[d] += xn;                                               \
        _Pragma("unroll")                                            \
        for (int j = 0; j < 8; ++j) {                                \
          ka[j] = fmaf(xn, Wk[d * 8 + j], ka[j]);                    \
          va[j] = fmaf(xn, Wv[d * 8 + j], va[j]);                    \
        }                                                            \
      }
      KA_STEP(x, 0) KA_STEP(y, 1) KA_STEP(z, 2) KA_STEP(w, 3)
#undef KA_STEP
    }

    const int n = n0 + t;
    float4* kp = (float4*)(kb + ((size_t)l * NN + n) * 8);
    float4* vp = (float4*)(vb + ((size_t)l * NN + n) * 8);
    kp[0] = make_float4(ka[0], ka[1], ka[2], ka[3]);
    kp[1] = make_float4(ka[4], ka[5], ka[6], ka[7]);
    vp[0] = make_float4(va[0], va[1], va[2], va[3]);
    vp[1] = make_float4(va[4], va[5], va[6], va[7]);
    __syncthreads();   // X4 about to be overwritten / reused
  }

  // xbar reduction: reuse X4 as float red[64][257] (16448 floats <= 17408)
  float* red = (float*)X4;
#pragma unroll
  for (int d = 0; d < DD; ++d) red[d * 257 + t] = xacc[d];
  __syncthreads();
  if (t < DD) {
    float s = 0.f;
    for (int i = 0; i < 256; ++i) s += red[t * 257 + i];
    xbar[(size_t)l * DD + t] = s * (1.f / NN);
  }
}

// ---------------------------------------------------------------------------
// Kernel B: per l: q = xbar@Wq (scaled), scores over n, softmax, o = attn@v.
// grid = L blocks, 512 threads = 8 waves; wave h owns head h. (unchanged)
// ---------------------------------------------------------------------------
__global__ __launch_bounds__(512) void kB(
    const float* __restrict__ kb, const float* __restrict__ vb,
    const float* __restrict__ xbar, const float* __restrict__ Wq,
    float* __restrict__ ob)
{
  __shared__ float qs[DD];
  __shared__ float ks[NN * 9];
  __shared__ float vs[NN * 9];
  const int l = blockIdx.x;
  const int t = threadIdx.x;
  const int h = t >> 6;
  const int lane = t & 63;

  const float* kl = kb + (size_t)l * NN * 8;
  const float* vl = vb + (size_t)l * NN * 8;
#pragma unroll
  for (int i = 0; i < 8; ++i) {
    const int idx = i * 512 + t;
    const int n = idx >> 3, j = idx & 7;
    ks[n*9 + j] = kl[idx];
    vs[n*9 + j] = vl[idx];
  }
  if (t < DD) {
    float acc = 0.f;
    for (int d = 0; d < DD; ++d) acc = fmaf(xbar[l*DD + d], Wq[d*DD + t], acc);
    qs[t] = acc * 0.35355339059327373f;
  }
  __syncthreads();

  float sc[8];
  float m = -1e30f;
#pragma unroll
  for (int i = 0; i < 8; ++i) {
    const int n = i * 64 + lane;
    float s = 0.f;
#pragma unroll
    for (int d = 0; d < 8; ++d) s = fmaf(qs[h*8 + d], ks[n*9 + d], s);
    sc[i] = s;
    m = fmaxf(m, s);
  }
#pragma unroll
  for (int off = 32; off; off >>= 1) m = fmaxf(m, __shfl_xor(m, off));
  float ssum = 0.f;
#pragma unroll
  for (int i = 0; i < 8; ++i) { sc[i] = __expf(sc[i] - m); ssum += sc[i]; }
#pragma unroll
  for (int off = 32; off; off >>= 1) ssum += __shfl_xor(ssum, off);
  const float inv = 1.f / ssum;

  float oacc[8];
#pragma unroll
  for (int d = 0; d < 8; ++d) oacc[d] = 0.f;
#pragma unroll
  for (int i = 0; i < 8; ++i) {
    const int n = i * 64 + lane;
#pragma unroll
    for (int d = 0; d < 8; ++d) oacc[d] = fmaf(sc[i], vs[n*9 + d], oacc[d]);
  }
#pragma unroll
  for (int d = 0; d < 8; ++d) {
#pragma unroll
    for (int off = 32; off; off >>= 1) oacc[d] += __shfl_xor(oacc[d], off);
  }
  if (lane == 0) {
    float4* op = (float4*)(ob + (size_t)l * DD + h * 8);
    op[0] = make_float4(oacc[0]*inv, oacc[1]*inv, oacc[2]*inv, oacc[3]*inv);
    op[1] = make_float4(oacc[4]*inv, oacc[5]*inv, oacc[6]*inv, oacc[7]*inv);
  }
}

// ---------------------------------------------------------------------------
// Kernel C: 64 rows/block, 4 threads per row (part p = wave id owns 16 of the
// 64 output columns). LDS 17.4 KB -> ~6 blocks/CU. Weights wave-uniform via
// readfirstlane -> s_load.  LN -> mv1(Wg) -> sigmoid*o -> mv2(Wout) -> out.
// ---------------------------------------------------------------------------
__global__ __launch_bounds__(256, 6) void kC(
    const float* __restrict__ msa, const float* __restrict__ lnw, const float* __restrict__ lnb,
    const float* __restrict__ Wg, const float* __restrict__ bg,
    const float* __restrict__ ob, const float* __restrict__ Wout, const float* __restrict__ bout,
    float* __restrict__ out)
{
  __shared__ float4 X4[64][17];   // 17408 B
  const int t = threadIdx.x;
  const int r = t & 63;
  const int pu = __builtin_amdgcn_readfirstlane(t >> 6);  // wave-uniform part id
  const size_t rowbase = (size_t)blockIdx.x * 64;

  // coalesced stage: 64 rows = 16 KB contiguous
  const float4* gp = (const float4*)(msa + rowbase * DD);
#pragma unroll
  for (int j = 0; j < 4; ++j) {
    const int idx = j * 256 + t;
    X4[idx >> 4][idx & 15] = gp[idx];
  }
  __syncthreads();

  // LN stats on row r (one pass)
  float s = 0.f, s2 = 0.f;
#pragma unroll
  for (int i = 0; i < 16; ++i) {
    const float4 f = X4[r][i];
    s += (f.x + f.y) + (f.z + f.w);
    s2 = fmaf(f.x, f.x, s2); s2 = fmaf(f.y, f.y, s2);
    s2 = fmaf(f.z, f.z, s2); s2 = fmaf(f.w, f.w, s2);
  }
  const float mu = s * (1.f / DD);
  const float rs = rsqrtf(fmaf(-mu, mu, s2 * (1.f / DD)) + EPSF);

  // mv1: acc[j] = sum_d xn_d * Wg[d][pu*16+j]
  float acc[16];
#pragma unroll
  for (int j = 0; j < 16; ++j) acc[j] = 0.f;
  const float* Wgp = Wg + pu * 16;
#pragma unroll
  for (int i = 0; i < 16; ++i) {
    const float4 f = X4[r][i];
#define KC_STEP(comp, c4)                                            \
    {                                                                \
      const int d = 4 * i + (c4);                                    \
      const float xn = fmaf((f.comp - mu) * rs, lnw[d], lnb[d]);     \
      _Pragma("unroll")                                              \
      for (int j = 0; j < 16; ++j)                                   \
        acc[j] = fmaf(xn, Wgp[d * DD + j], acc[j]);                  \
    }
    KC_STEP(x, 0) KC_STEP(y, 1) KC_STEP(z, 2) KC_STEP(w, 3)
#undef KC_STEP
  }

  // t_j = sigmoid(acc_j + bg_j) * o[l][j]
  const int l = (int)((rowbase + r) & (LL - 1));
  const float* obp = ob + (size_t)l * DD + pu * 16;
#pragma unroll
  for (int q = 0; q < 4; ++q) {
    const float4 ov = *(const float4*)(obp + q * 4);
    acc[q*4+0] = ov.x / (1.f + __expf(-(acc[q*4+0] + bg[pu*16 + q*4+0])));
    acc[q*4+1] = ov.y / (1.f + __expf(-(acc[q*4+1] + bg[pu*16 + q*4+1])));
    acc[q*4+2] = ov.z / (1.f + __expf(-(acc[q*4+2] + bg[pu*16 + q*4+2])));
    acc[q*4+3] = ov.w / (1.f + __expf(-(acc[q*4+3] + bg[pu*16 + q*4+3])));
  }
  __syncthreads();   // all parts done reading raw X rows
#pragma unroll
  for (int q = 0; q < 4; ++q)
    X4[r][pu * 4 + q] = make_float4(acc[q*4+0], acc[q*4+1], acc[q*4+2], acc[q*4+3]);
  __syncthreads();

  // mv2: out[j] = bout[j] + sum_d t_d * Wout[d][pu*16+j]
#pragma unroll
  for (int j = 0; j < 16; ++j) acc[j] = bout[pu * 16 + j];
  const float* Wop = Wout + pu * 16;
#pragma unroll
  for (int i = 0; i < 16; ++i) {
    const float4 f = X4[r][i];
#define KC2_STEP(comp, c4)                                           \
    {                                                                \
      const int d = 4 * i + (c4);                                    \
      const float td = f.comp;                                       \
      _Pragma("unroll")                                              \
      for (int j = 0; j < 16; ++j)                                   \
        acc[j] = fmaf(td, Wop[d * DD + j], acc[j]);                  \
    }
    KC2_STEP(x, 0) KC2_STEP(y, 1) KC2_STEP(z, 2) KC2_STEP(w, 3)
#undef KC2_STEP
  }
  __syncthreads();   // all parts done reading t rows
#pragma unroll
  for (int q = 0; q < 4; ++q)
    X4[r][pu * 4 + q] = make_float4(acc[q*4+0], acc[q*4+1], acc[q*4+2], acc[q*4+3]);
  __syncthreads();

  // coalesced store-out
  float4* op = (float4*)(out + rowbase * DD);
#pragma unroll
  for (int j = 0; j < 4; ++j) {
    const int idx = j * 256 + t;
    op[idx] = X4[idx >> 4][idx & 15];
  }
}

// ---------------------------------------------------------------------------
extern "C" void kernel_launch(void* const* d_in, const int* in_sizes, int n_in,
                              void* d_out, int out_size, void* d_ws, size_t ws_size,
                              hipStream_t stream)
{
  const float* msa  = (const float*)d_in[0];
  const float* lnw  = (const float*)d_in[1];
  const float* lnb  = (const float*)d_in[2];
  const float* Wq   = (const float*)d_in[3];
  const float* Wk   = (const float*)d_in[4];
  const float* Wv   = (const float*)d_in[5];
  const float* Wg   = (const float*)d_in[6];
  const float* bg   = (const float*)d_in[7];
  const float* Wout = (const float*)d_in[8];
  const float* bout = (const float*)d_in[9];
  float* out = (float*)d_out;

  float* kb   = (float*)d_ws;                       // (L, N, 8) 16 MB
  float* vb   = kb + (size_t)LL * NN * 8;           // (L, N, 8) 16 MB
  float* xbar = vb + (size_t)LL * NN * 8;           // (L, 64)  256 KB
  float* ob   = xbar + (size_t)LL * DD;             // (L, 64)  256 KB

  kA<<<LL, 256, 0, stream>>>(msa, lnw, lnb, Wk, Wv, kb, vb, xbar);
  kB<<<LL, 512, 0, stream>>>(kb, vb, xbar, Wq, ob);
  kC<<<(NN * LL) / 64, 256, 0, stream>>>(msa, lnw, lnb, Wg, bg, ob, Wout, bout, out);
}